// Round 9
// baseline (67.012 us; speedup 1.0000x reference)
//
#include <hip/hip_runtime.h>

// Inverse 1D wavelet reconstruction via COMPOSED polyphase filters.
// out = S_h^4 s + S_h^3 S_g d3 + S_h^2 S_g d2 + S_h S_g d1 + S_g d0
// S_f(x)[n] = sum_tau x[tau] w_f[n-2tau], w_f[v] = f[v+2], v in [-2,3].
// W_k[v] = sum_u W_{k-1}[u] w_h[v-2u]; supports: 16 (stride4), 36 (stride8),
// 76 (stride16). Tap windows per phase rr = n&15 SHIFT with rr:
//   s,d3 (stride16): offsets [-2..2] always cover [-30,45]  (5 taps)
//   d2   (stride 8): base m2 = (rr-14)>>3, 5 taps
//   d1   (stride 4): base m1 = (rr-6)>>2, exactly 4 taps
//   d0   (stride 2): base m0 = (rr-2)>>1, exactly 3 taps
// Pad-affected outputs reach only 30 from each end -> boundary block (x==32)
// runs the verified cascade for [0,64) and [L4-64,L4).
#define C_CH 64
#define L0   16384

typedef float f32x2 __attribute__((ext_vector_type(2)));

struct Taps {
    float he0, he1, he2, ho0, ho1, ho2;
    float ge0, ge1, ge2, go0, go1, go2;
};

// ---------------- generic cascade level (boundary block only) --------------
template <bool GLOBAL_OUT>
__device__ __forceinline__ void synth_level(
    const float* __restrict__ xp, int xlo, int Lx,
    const float* __restrict__ dp,
    float* __restrict__ yp, int ylo, int yhi,
    const Taps& T, int tid, int nthr)
{
    const int tlo = ylo >> 1, thi = yhi >> 1;
    const int tA = (tlo == 0) ? 1 : tlo;
    const int tB = (thi == Lx - 1) ? (thi - 1) : thi;

    for (int t = tA + tid; t <= tB; t += nthr) {
        const float a0 = xp[t-1-xlo], a1 = xp[t-xlo], a2 = xp[t+1-xlo];
        const float d0 = dp[t-1], d1 = dp[t], d2 = dp[t+1];
        const float ve = a0*T.he0 + a1*T.he1 + a2*T.he2 + d0*T.ge0 + d1*T.ge1 + d2*T.ge2;
        const float vo = a0*T.ho0 + a1*T.ho1 + a2*T.ho2 + d0*T.go0 + d1*T.go1 + d2*T.go2;
        *reinterpret_cast<f32x2*>(yp + (2*t - ylo)) = f32x2{ve, vo};
    }
    if (tid == 0) {
        if (tlo == 0) {  // t=0: xpad[0] = 2x0 - x1
            const float x0 = xp[0-xlo], x1 = xp[1-xlo];
            const float dd0 = dp[0], dd1 = dp[1];
            const float a0 = 2.0f*x0 - x1, b0 = 2.0f*dd0 - dd1;
            const float ve = a0*T.he0 + x0*T.he1 + x1*T.he2 + b0*T.ge0 + dd0*T.ge1 + dd1*T.ge2;
            const float vo = a0*T.ho0 + x0*T.ho1 + x1*T.ho2 + b0*T.go0 + dd0*T.go1 + dd1*T.go2;
            *reinterpret_cast<f32x2*>(yp + (0 - ylo)) = f32x2{ve, vo};
        }
        if (thi == Lx - 1) {  // t=Lx-1: xpad[Lx+1] = 2x[L-1]-x[L-2]
            const int t = Lx - 1;
            const float xm = xp[t-1-xlo], xl = xp[t-xlo];
            const float dm = dp[t-1], dl = dp[t];
            const float a2 = 2.0f*xl - xm, b2 = 2.0f*dl - dm;
            const float ve = xm*T.he0 + xl*T.he1 + a2*T.he2 + dm*T.ge0 + dl*T.ge1 + b2*T.ge2;
            const float vo = xm*T.ho0 + xl*T.ho1 + a2*T.ho2 + dm*T.go0 + dl*T.go1 + b2*T.go2;
            *reinterpret_cast<f32x2*>(yp + (2*t - ylo)) = f32x2{ve, vo};
        }
    }
}

__global__ __launch_bounds__(256) void iwt_composed_kernel(
    const float* __restrict__ sig, const float* __restrict__ d0,
    const float* __restrict__ d1,  const float* __restrict__ d2,
    const float* __restrict__ d3,  const float* __restrict__ h,
    const float* __restrict__ g,   float* __restrict__ out)
{
    const int c   = blockIdx.y;
    const int tid = threadIdx.x;

    const int L1 = 2*L0, L2 = 4*L0, L3 = 8*L0, L4 = 16*L0;

    // coeff buffers (zero-padded):
    // [  0, 80): c4h, idx = v+32, valid idx [2,77]   (W4h, v in [-30,45])
    // [ 80,160): c4g, idx = v+32, valid idx [2,77]
    // [160,200): c3g, idx = v+18, valid idx [4,39]   (W3g, v in [-14,21])
    // [200,216): c2g, idx = v+6,  all 16 valid       (W2g, v in [-6,9])
    // [216,224): c1g, idx = v+2,  valid idx [0,5]    (w_g)
    __shared__ float cbuf[224];
    __shared__ float w2h[16], w2g[16], w3h[36], w3g[36];
    __shared__ __align__(16) float s1b[48], s2b[48], s3b[48];

    const float* s0p = sig + (size_t)c * L0;
    const float* d3p = d3  + (size_t)c * L0;
    const float* d2p = d2  + (size_t)c * L1;
    const float* d1p = d1  + (size_t)c * L2;
    const float* d0p = d0  + (size_t)c * L3;
    float*       outp = out + (size_t)c * L4;

    if (blockIdx.x == 32) {
        // ---------- boundary block: cascade for [0,64) and [L4-64, L4) ------
        Taps T;
        T.he0 = h[4]; T.he1 = h[2]; T.he2 = h[0];
        T.ho0 = h[5]; T.ho1 = h[3]; T.ho2 = h[1];
        T.ge0 = g[4]; T.ge1 = g[2]; T.ge2 = g[0];
        T.go0 = g[5]; T.go1 = g[3]; T.go2 = g[1];

        synth_level<false>(s0p, 0, L0, d3p, s1b, 0, 9,  T, tid, 256);
        __syncthreads();
        synth_level<false>(s1b, 0, L1, d2p, s2b, 0, 17, T, tid, 256);
        __syncthreads();
        synth_level<false>(s2b, 0, L2, d1p, s3b, 0, 32, T, tid, 256);
        __syncthreads();
        synth_level<true >(s3b, 0, L3, d0p, outp, 0, 63, T, tid, 256);
        __syncthreads();
        synth_level<false>(s0p, 0,     L0, d3p, s1b, L1-12, L1-1, T, tid, 256);
        __syncthreads();
        synth_level<false>(s1b, L1-12, L1, d2p, s2b, L2-20, L2-1, T, tid, 256);
        __syncthreads();
        synth_level<false>(s2b, L2-20, L2, d1p, s3b, L3-36, L3-1, T, tid, 256);
        __syncthreads();
        synth_level<true >(s3b, L3-36, L3, d0p, outp + (L4-64), L4-64, L4-1, T, tid, 256);
        return;
    }

    // ---------------- interior: build composed filters in LDS --------------
    for (int i = tid; i < 224; i += 256) cbuf[i] = 0.0f;
    // phase A: W2h/W2g[v], v in [-6,9]
    if (tid < 32) {
        const float* f = (tid < 16) ? h : g;
        const int v = (tid & 15) - 6;
        float acc = 0.0f;
        for (int u = -2; u <= 3; ++u) {
            const int x = v - 2*u;
            if (x >= -2 && x <= 3) acc += f[u+2] * h[x+2];
        }
        if (tid < 16) w2h[v+6] = acc; else w2g[v+6] = acc;
    }
    __syncthreads();
    // phase B: W3h/W3g[v], v in [-14,21]
    if (tid < 72) {
        const bool hs = (tid < 36);
        const int v = (hs ? tid : tid - 36) - 14;
        const float* W2 = hs ? w2h : w2g;
        float acc = 0.0f;
        for (int u = -6; u <= 9; ++u) {
            const int x = v - 2*u;
            if (x >= -2 && x <= 3) acc += W2[u+6] * h[x+2];
        }
        if (hs) w3h[v+14] = acc; else w3g[v+14] = acc;
    }
    __syncthreads();
    // phase C: W4h/W4g[v], v in [-30,45]; plus copies of W3g/W2g/W1g
    if (tid < 152) {
        const bool hs = (tid < 76);
        const int v = (hs ? tid : tid - 76) - 30;
        const float* W3 = hs ? w3h : w3g;
        float acc = 0.0f;
        for (int u = -14; u <= 21; ++u) {
            const int x = v - 2*u;
            if (x >= -2 && x <= 3) acc += W3[u+14] * h[x+2];
        }
        cbuf[(hs ? 0 : 80) + v + 32] = acc;
    }
    if (tid >= 192 && tid < 228) cbuf[164 + (tid - 192)] = w3g[tid - 192]; // v=i-14 -> idx i+4
    if (tid >= 228 && tid < 244) cbuf[200 + (tid - 228)] = w2g[tid - 228]; // v=i-6  -> idx i
    if (tid >= 244 && tid < 250) cbuf[216 + (tid - 244)] = g[tid - 244];   // c1g[i]=g[i]
    __syncthreads();

    // ---------------- per-lane coefficient registers ------------------------
    // lane l: rr = l&15 (output phase), j = l>>4; n = nb + 16j + rr = nb + l.
    const int l  = tid & 63, wv = tid >> 6;
    const int rr = l & 15,  j  = l >> 4;
    const int m0 = (rr - 2)  >> 1;   // d0 base (3 taps)
    const int m1 = (rr - 6)  >> 2;   // d1 base (4 taps)
    const int m2 = (rr - 14) >> 3;   // d2 base (5 taps)

    float cS[5], cT[5], cU[5], cV[4], cW[3];
#pragma unroll
    for (int k = 0; k < 5; ++k) {
        cS[k] = cbuf[      rr - 16*k + 64];              // v = rr-16(k-2)
        cT[k] = cbuf[ 80 + rr - 16*k + 64];
        cU[k] = cbuf[160 + rr - 8*(m2+k) + 18];          // v = rr-8(m2+k)
    }
#pragma unroll
    for (int k = 0; k < 4; ++k)
        cV[k] = cbuf[200 + rr - 4*(m1+k) + 6];           // v = rr-4(m1+k)
#pragma unroll
    for (int i = 0; i < 3; ++i)
        cW[i] = cbuf[216 + rr - 2*(m0+i) + 2];           // v = rr-2(m0+i)

    // ---------------- streaming main loop -----------------------------------
    // interior outputs n in [64, L4-64): 4094 wave-rounds of 64 per channel.
    const int Wc = blockIdx.x * 4 + wv;    // wave id within channel, 0..127
    for (int it = 0; it < 32; ++it) {
        const int rho = Wc * 32 + it;
        if (rho >= 4094) break;
        const int nb = 64 + (rho << 6);
        const int q  = (nb >> 4) + j;      // = n>>4

        const float* sq = s0p + q;
        const float* tq = d3p + q;
        const float* uq = d2p + 2*q + m2;
        const float* vq = d1p + 4*q + m1;
        const float* wq = d0p + 8*q + m0;

        float acc;
        acc  = sq[-2]*cS[0] + sq[-1]*cS[1] + sq[0]*cS[2] + sq[1]*cS[3] + sq[2]*cS[4];
        acc += tq[-2]*cT[0] + tq[-1]*cT[1] + tq[0]*cT[2] + tq[1]*cT[3] + tq[2]*cT[4];
        acc += uq[0]*cU[0] + uq[1]*cU[1] + uq[2]*cU[2] + uq[3]*cU[3] + uq[4]*cU[4];
        acc += vq[0]*cV[0] + vq[1]*cV[1] + vq[2]*cV[2] + vq[3]*cV[3];
        acc += wq[0]*cW[0] + wq[1]*cW[1] + wq[2]*cW[2];

        __builtin_nontemporal_store(acc, outp + nb + (j << 4) + rr);
    }
}

extern "C" void kernel_launch(void* const* d_in, const int* in_sizes, int n_in,
                              void* d_out, int out_size, void* d_ws, size_t ws_size,
                              hipStream_t stream) {
    const float* sig = (const float*)d_in[0];
    const float* d0  = (const float*)d_in[1];
    const float* d1  = (const float*)d_in[2];
    const float* d2  = (const float*)d_in[3];
    const float* d3  = (const float*)d_in[4];
    const float* h   = (const float*)d_in[5];
    const float* g   = (const float*)d_in[6];
    float* out = (float*)d_out;

    dim3 grid(33, C_CH);   // x: 0..31 interior slabs, 32 = boundary block
    iwt_composed_kernel<<<grid, 256, 0, stream>>>(sig, d0, d1, d2, d3, h, g, out);
}